// Round 1
// baseline (495.701 us; speedup 1.0000x reference)
//
#include <hip/hip_runtime.h>
#include <stdint.h>
#include <math.h>

typedef unsigned short u16;
typedef __attribute__((ext_vector_type(8))) short short8;
typedef __attribute__((ext_vector_type(4))) float f32x4;

__device__ __forceinline__ float bf2f(u16 u){
  union { unsigned int i; float f; } v; v.i = ((unsigned int)u) << 16; return v.f;
}
__device__ __forceinline__ u16 f2bf(float f){
  union { float f; unsigned int i; } v; v.f = f;
  return (u16)((v.i + 0x7FFFu + ((v.i >> 16) & 1u)) >> 16);
}

// ---------------- LayerNorm + x->bf16 (one row per block) ----------------
__global__ void ln_prep(const float* __restrict__ x, const float* __restrict__ g,
                        const float* __restrict__ bta, u16* __restrict__ h,
                        u16* __restrict__ xb, float* __restrict__ loss){
  if (blockIdx.x == 0 && threadIdx.x == 0) loss[0] = 0.f;
  int row = blockIdx.x, tid = threadIdx.x;
  const float4* xr = (const float4*)(x + (size_t)row * 1024);
  float4 v = xr[tid];
  float s  = v.x + v.y + v.z + v.w;
  float s2 = v.x*v.x + v.y*v.y + v.z*v.z + v.w*v.w;
  #pragma unroll
  for (int o = 32; o > 0; o >>= 1){ s += __shfl_down(s, o); s2 += __shfl_down(s2, o); }
  __shared__ float red[8];
  if ((tid & 63) == 0){ red[tid >> 6] = s; red[4 + (tid >> 6)] = s2; }
  __syncthreads();
  float ts = red[0]+red[1]+red[2]+red[3];
  float t2 = red[4]+red[5]+red[6]+red[7];
  float mu   = ts * (1.0f/1024.0f);
  float var  = t2 * (1.0f/1024.0f) - mu*mu;
  float rstd = rsqrtf(var + 1e-5f);
  float4 gg = ((const float4*)g)[tid];
  float4 bb = ((const float4*)bta)[tid];
  ushort4 hv, xv;
  hv.x = f2bf((v.x-mu)*rstd*gg.x + bb.x);
  hv.y = f2bf((v.y-mu)*rstd*gg.y + bb.y);
  hv.z = f2bf((v.z-mu)*rstd*gg.z + bb.z);
  hv.w = f2bf((v.w-mu)*rstd*gg.w + bb.w);
  xv.x = f2bf(v.x); xv.y = f2bf(v.y); xv.z = f2bf(v.z); xv.w = f2bf(v.w);
  ((ushort4*)h )[(size_t)row*256 + tid] = hv;
  ((ushort4*)xb)[(size_t)row*256 + tid] = xv;
}

// ---------------- fp32 -> bf16 weight conversion (5 matrices) ----------------
__global__ void conv5(const float* __restrict__ a, const float* __restrict__ b,
                      const float* __restrict__ c, const float* __restrict__ d,
                      const float* __restrict__ e,
                      u16* oa, u16* ob, u16* oc, u16* od, u16* oe){
  int sel = blockIdx.y;
  const float* s = sel==0?a : sel==1?b : sel==2?c : sel==3?d : e;
  u16* o = sel==0?oa : sel==1?ob : sel==2?oc : sel==3?od : oe;
  int i = blockIdx.x*256 + threadIdx.x;   // 262144 float4's
  float4 v = ((const float4*)s)[i];
  ushort4 r; r.x=f2bf(v.x); r.y=f2bf(v.y); r.z=f2bf(v.z); r.w=f2bf(v.w);
  ((ushort4*)o)[i] = r;
}

// --------- WeffT[d][e] = W0[e][d] + sum_r A[e][r]*B[r][d], bf16 out ---------
__global__ void weff_k(const float* __restrict__ W0, const float* __restrict__ Ai,
                       const float* __restrict__ Bi, u16* __restrict__ Wet){
  __shared__ float tile[32][33];
  int d0 = blockIdx.x*32, e0 = blockIdx.y*32;
  int tid = threadIdx.x;
  int lr = tid >> 5, lc = tid & 31;
  #pragma unroll
  for (int s = 0; s < 4; ++s){
    int e = e0 + s*8 + lr, d = d0 + lc;
    float v = W0[(size_t)e*1024 + d];
    #pragma unroll
    for (int r = 0; r < 8; ++r) v += Ai[e*8 + r] * Bi[(size_t)r*1024 + d];
    tile[s*8 + lr][lc] = v;
  }
  __syncthreads();
  #pragma unroll
  for (int s = 0; s < 4; ++s){
    int d = d0 + s*8 + lr, e = e0 + lc;
    Wet[(size_t)d*1024 + e] = f2bf(tile[lc][s*8 + lr]);
  }
}

// =====================================================================
// 256x256 MFMA GEMM: C[m,n] = sum_k A[m,k]*Bm[n,k]  (K=1024)
// 8 waves (2Mx4N), K sliced at 32, 4-slot LDS ring (128 KiB),
// stage-ahead 3 slices, counted vmcnt(8) (never 0 in main loop),
// XOR bank swizzle (both-sides: pre-swizzled global src + swizzled read),
// s_setprio(1) around the MFMA cluster.
//
// LDS layout per slot per matrix: 128 "ldsrows" x 128 B; ldsrow j packs
// m-rows {2j, 2j+1} (32 k-elems each). 16-B slots: logical s = p*4+q
// (p = m-row parity, q = k-chunk); stored at phys = s ^ (j&7).
// =====================================================================
template<int EPI>
__device__ __forceinline__ void gemm256_body(const u16* __restrict__ A, const u16* __restrict__ Bm,
    u16* __restrict__ Cb, float* __restrict__ Cf, const float* __restrict__ lsg,
    const float* __restrict__ xres, int mblk, int nblk)
{
  __shared__ u16 As[4][8192];
  __shared__ u16 Bs[4][8192];
  const int tid  = threadIdx.x;
  const int lane = tid & 63;
  const int w    = tid >> 6;            // 0..7
  const int wm = w >> 2, wn = w & 3;    // 2 x 4 wave grid
  const int l15 = lane & 15, quad = lane >> 4;
  const int m0 = mblk * 256, n0 = nblk * 256;

  // ---- staging: linear LDS dest, inverse-swizzled global source ----
  // lane l writes ldsrow j = it*64 + w*8 + (l>>3), phys slot (l&7).
  // logical slot there = (l&7) ^ (j&7) = (l&7) ^ (l>>3).
  const int sl   = (lane & 7) ^ (lane >> 3);
  const int srow = 2*(w*8 + (lane >> 3)) + (sl >> 2);
  const int scol = (sl & 3) * 8;
  const u16* gA = A  + (size_t)(m0 + srow)*1024 + scol;
  const u16* gB = Bm + (size_t)(n0 + srow)*1024 + scol;
  const int ldsOff = w * 512;           // elems; it=1 adds 4096

  // ---- swizzled read addresses (elems) ----
  // frag row m = base + i*16 + l15 -> ldsrow = base/2 + i*8 + (l15>>1),
  // logical slot = (l15&1)*4 + quad, phys = logical ^ (l15>>1).
  const int phys8 = (((((l15 & 1) << 2) | quad) ^ (l15 >> 1))) * 8;
  const int rdA = (wm*64 + (l15 >> 1))*64 + phys8;
  const int rdB = (wn*32 + (l15 >> 1))*64 + phys8;

  f32x4 acc[8][4] = {};

#define STAGE(T) do{ \
    const int _s = (T) & 3; \
    const size_t _k = (size_t)(T) * 32; \
    __builtin_amdgcn_global_load_lds((const __attribute__((address_space(1))) unsigned int*)(gA + _k), \
        (__attribute__((address_space(3))) unsigned int*)(&As[_s][ldsOff]), 16, 0, 0); \
    __builtin_amdgcn_global_load_lds((const __attribute__((address_space(1))) unsigned int*)(gA + _k + 131072), \
        (__attribute__((address_space(3))) unsigned int*)(&As[_s][ldsOff + 4096]), 16, 0, 0); \
    __builtin_amdgcn_global_load_lds((const __attribute__((address_space(1))) unsigned int*)(gB + _k), \
        (__attribute__((address_space(3))) unsigned int*)(&Bs[_s][ldsOff]), 16, 0, 0); \
    __builtin_amdgcn_global_load_lds((const __attribute__((address_space(1))) unsigned int*)(gB + _k + 131072), \
        (__attribute__((address_space(3))) unsigned int*)(&Bs[_s][ldsOff + 4096]), 16, 0, 0); \
  }while(0)

#define COMPUTE(T) do{ \
    const int _s = (T) & 3; \
    const u16* _as = &As[_s][0]; \
    const u16* _bs = &Bs[_s][0]; \
    short8 afv[8], bfv[4]; \
    _Pragma("unroll") \
    for (int _j = 0; _j < 4; ++_j) bfv[_j] = *(const short8*)(_bs + rdB + _j*512); \
    _Pragma("unroll") \
    for (int _i = 0; _i < 8; ++_i) afv[_i] = *(const short8*)(_as + rdA + _i*512); \
    __builtin_amdgcn_s_setprio(1); \
    _Pragma("unroll") \
    for (int _i = 0; _i < 8; ++_i){ \
      _Pragma("unroll") \
      for (int _j = 0; _j < 4; ++_j) \
        acc[_i][_j] = __builtin_amdgcn_mfma_f32_16x16x32_bf16(afv[_i], bfv[_j], acc[_i][_j], 0, 0, 0); \
    } \
    __builtin_amdgcn_s_setprio(0); \
  }while(0)

  // prologue: 3 slices in flight
  STAGE(0); STAGE(1); STAGE(2);

  // main loop: phases 0..28 stage slice t+3 (last stage: slice 31)
  #pragma unroll 1
  for (int t = 0; t < 29; ++t){
    asm volatile("s_waitcnt vmcnt(8)" ::: "memory");  // slice t landed; t+1,t+2 in flight
    __builtin_amdgcn_s_barrier();
    __builtin_amdgcn_sched_barrier(0);
    STAGE(t + 3);
    COMPUTE(t);
  }
  // tail: drain gradually (8 -> 4 -> 0)
  asm volatile("s_waitcnt vmcnt(8)" ::: "memory");
  __builtin_amdgcn_s_barrier();
  __builtin_amdgcn_sched_barrier(0);
  COMPUTE(29);
  asm volatile("s_waitcnt vmcnt(4)" ::: "memory");
  __builtin_amdgcn_s_barrier();
  __builtin_amdgcn_sched_barrier(0);
  COMPUTE(30);
  asm volatile("s_waitcnt vmcnt(0)" ::: "memory");
  __builtin_amdgcn_s_barrier();
  __builtin_amdgcn_sched_barrier(0);
  COMPUTE(31);
#undef STAGE
#undef COMPUTE

  // ---- epilogue: C/D layout col=lane&15, row=quad*4+r (verified) ----
  const int rbase = quad * 4;
  if (EPI == 0){
    #pragma unroll
    for (int i = 0; i < 8; ++i){
      int row = m0 + wm*128 + i*16 + rbase;
      #pragma unroll
      for (int j = 0; j < 4; ++j){
        int col = n0 + wn*64 + j*16 + l15;
        #pragma unroll
        for (int r = 0; r < 4; ++r)
          Cb[(size_t)(row + r)*1024 + col] = f2bf(acc[i][j][r]);
      }
    }
  } else {
    float lsv[4];
    #pragma unroll
    for (int j = 0; j < 4; ++j) lsv[j] = lsg[n0 + wn*64 + j*16 + l15];
    #pragma unroll
    for (int i = 0; i < 8; ++i){
      int row = m0 + wm*128 + i*16 + rbase;
      #pragma unroll
      for (int j = 0; j < 4; ++j){
        int col = n0 + wn*64 + j*16 + l15;
        #pragma unroll
        for (int r = 0; r < 4; ++r){
          size_t idx = (size_t)(row + r)*1024 + col;
          Cf[idx] = acc[i][j][r] * lsv[j] + xres[idx];
        }
      }
    }
  }
}

// fused Q/K/V/Gate GEMM: 1024 blocks; XCD-swizzled, A-panel-major layout
__global__ __launch_bounds__(512, 2) void gemm_qkvg(
    const u16* __restrict__ h, const u16* __restrict__ xb,
    const u16* __restrict__ Wqb, const u16* __restrict__ Wkb,
    const u16* __restrict__ Wvb, const u16* __restrict__ Wgb,
    u16* __restrict__ Qb, u16* __restrict__ Kb,
    u16* __restrict__ Vb, u16* __restrict__ Gb){
  int bid = blockIdx.x;                       // 1024 = 8 XCD chunks of 128
  int swz = (bid & 7) * 128 + (bid >> 3);     // bijective (1024 % 8 == 0)
  int mblk = swz >> 4;                        // 64 m-blocks; 8 per XCD chunk
  int rem  = swz & 15;
  int sel  = rem >> 2, nblk = rem & 3;
  const u16* A  = (sel == 3) ? xb : h;
  const u16* Bm = sel==0?Wqb : sel==1?Wkb : sel==2?Wvb : Wgb;
  u16* Out      = sel==0?Qb  : sel==1?Kb  : sel==2?Vb  : Gb;
  gemm256_body<0>(A, Bm, Out, nullptr, nullptr, nullptr, mblk, nblk);
}

__global__ __launch_bounds__(512, 2) void gemm_plain(
    const u16* __restrict__ A, const u16* __restrict__ Bm, u16* __restrict__ C){
  int bid = blockIdx.x;                       // 256
  int swz = (bid & 7) * 32 + (bid >> 3);
  gemm256_body<0>(A, Bm, C, nullptr, nullptr, nullptr, swz >> 2, swz & 3);
}

__global__ __launch_bounds__(512, 2) void gemm_final(
    const u16* __restrict__ A, const u16* __restrict__ Bm,
    float* __restrict__ C, const float* __restrict__ lsg,
    const float* __restrict__ xres){
  int bid = blockIdx.x;                       // 256
  int swz = (bid & 7) * 32 + (bid >> 3);
  gemm256_body<1>(A, Bm, nullptr, C, lsg, xres, swz >> 2, swz & 3);
}

// ---------------- scan pass 1: per-chunk gradient sums + loss ----------------
// grid (4, 32, 4): (c-block, chunk, batch); chunk = 128 timesteps
__global__ void scan1(const u16* __restrict__ Kb, const u16* __restrict__ Vb,
                      const u16* __restrict__ Yb, float* __restrict__ part,
                      float* __restrict__ loss){
  int tid = threadIdx.x;
  int c = blockIdx.x*256 + tid;
  int ch = blockIdx.y, b = blockIdx.z;
  size_t base = ((size_t)b*4096 + (size_t)ch*128)*1024 + c;
  float g = 0.f, ls = 0.f;
  #pragma unroll 8
  for (int t = 0; t < 128; ++t){
    size_t idx = base + (size_t)t*1024;
    float kv = bf2f(Kb[idx]), vv = bf2f(Vb[idx]), yv = bf2f(Yb[idx]);
    float e = yv - vv;
    g += kv*e; ls += e*e;
  }
  part[((size_t)(b*32 + ch))*1024 + c] = g;
  #pragma unroll
  for (int o = 32; o > 0; o >>= 1) ls += __shfl_down(ls, o);
  __shared__ float red[4];
  if ((tid & 63) == 0) red[tid >> 6] = ls;
  __syncthreads();
  if (tid == 0) atomicAdd(loss, red[0]+red[1]+red[2]+red[3]);
}

// -------- scan pass 2: out_pre = (y0 - Q*lr*shift*pos_scale)*sigmoid(G) ------
__global__ void scan2(const u16* __restrict__ Kb, const u16* __restrict__ Vb,
                      const u16* __restrict__ Yb, const u16* __restrict__ Qb,
                      const u16* __restrict__ Gb, const float* __restrict__ part,
                      const float* __restrict__ llr, u16* __restrict__ OutPre){
  int tid = threadIdx.x;
  int c = blockIdx.x*256 + tid;
  int ch = blockIdx.y, b = blockIdx.z;
  float run = 0.f;
  for (int j = 0; j < ch; ++j) run += part[((size_t)(b*32 + j))*1024 + c];
  float lrc = fminf(expf(llr[c]), 1.0f);
  size_t base = ((size_t)b*4096 + (size_t)ch*128)*1024 + c;
  #pragma unroll 4
  for (int t = 0; t < 128; ++t){
    size_t idx = base + (size_t)t*1024;
    float kv = bf2f(Kb[idx]), vv = bf2f(Vb[idx]), yv = bf2f(Yb[idx]);
    float qv = bf2f(Qb[idx]), gl = bf2f(Gb[idx]);
    float e = yv - vv;
    int tg = ch*128 + t + 1;
    float ps = 1.0f/(1.0f + 0.1f*logf((float)tg));
    float gate = 1.0f/(1.0f + expf(-gl));
    float o = (yv - qv*lrc*run*ps) * gate;
    OutPre[idx] = f2bf(o);     // same buffer as Qb: read-before-write per element
    run += kv*e;
  }
}

__global__ void finloss(const float* __restrict__ loss, float* __restrict__ o){
  o[0] = loss[0] * (1.0f/16777216.0f);
}

extern "C" void kernel_launch(void* const* d_in, const int* in_sizes, int n_in,
                              void* d_out, int out_size, void* d_ws, size_t ws_size,
                              hipStream_t stream){
  const float* x   = (const float*)d_in[0];
  const float* W0  = (const float*)d_in[1];
  const float* Ai  = (const float*)d_in[2];
  const float* Bi  = (const float*)d_in[3];
  const float* llr = (const float*)d_in[4];
  const float* Wq  = (const float*)d_in[5];
  const float* Wk  = (const float*)d_in[6];
  const float* Wv  = (const float*)d_in[7];
  const float* Wo  = (const float*)d_in[8];
  const float* Wg  = (const float*)d_in[9];
  const float* lng = (const float*)d_in[10];
  const float* lnb = (const float*)d_in[11];
  const float* lsg = (const float*)d_in[12];
  float* out = (float*)d_out;

  const size_t TOK = 16384, CC = 1024;
  char* p = (char*)d_ws;
  float* loss = (float*)p; p += 256;
  u16* h   = (u16*)p; p += TOK*CC*2;   // reused as y0 after GEMM1
  u16* xb  = (u16*)p; p += TOK*CC*2;
  u16* Qb  = (u16*)p; p += TOK*CC*2;   // reused as out_pre in scan2
  u16* Kb  = (u16*)p; p += TOK*CC*2;
  u16* Vb  = (u16*)p; p += TOK*CC*2;
  u16* Gb  = (u16*)p; p += TOK*CC*2;
  u16* Wqb = (u16*)p; p += CC*CC*2;
  u16* Wkb = (u16*)p; p += CC*CC*2;
  u16* Wvb = (u16*)p; p += CC*CC*2;
  u16* Wgb = (u16*)p; p += CC*CC*2;
  u16* Wob = (u16*)p; p += CC*CC*2;
  u16* Wet = (u16*)p; p += CC*CC*2;
  float* part = (float*)p; p += (size_t)4*32*1024*4;

  ln_prep<<<16384, 256, 0, stream>>>(x, lng, lnb, h, xb, loss);
  conv5<<<dim3(1024, 5), 256, 0, stream>>>(Wq, Wk, Wv, Wg, Wo, Wqb, Wkb, Wvb, Wgb, Wob);
  weff_k<<<dim3(32, 32), 256, 0, stream>>>(W0, Ai, Bi, Wet);
  gemm_qkvg<<<1024, 512, 0, stream>>>(h, xb, Wqb, Wkb, Wvb, Wgb, Qb, Kb, Vb, Gb);
  gemm_plain<<<256, 512, 0, stream>>>(Kb, Wet, h);                 // y0 -> h buffer
  scan1<<<dim3(4, 32, 4), 256, 0, stream>>>(Kb, Vb, h, part, loss);
  scan2<<<dim3(4, 32, 4), 256, 0, stream>>>(Kb, Vb, h, Qb, Gb, part, llr, Qb);
  gemm_final<<<256, 512, 0, stream>>>(Qb, Wob, out, lsg, x);
  finloss<<<1, 1, 0, stream>>>(loss, out + 16777216);
}

// Round 2
// 458.124 us; speedup vs baseline: 1.0820x; 1.0820x over previous
//
#include <hip/hip_runtime.h>
#include <stdint.h>
#include <math.h>

typedef unsigned short u16;
typedef __attribute__((ext_vector_type(8))) short short8;
typedef __attribute__((ext_vector_type(4))) float f32x4;

__device__ __forceinline__ float bf2f(u16 u){
  union { unsigned int i; float f; } v; v.i = ((unsigned int)u) << 16; return v.f;
}
__device__ __forceinline__ u16 f2bf(float f){
  union { float f; unsigned int i; } v; v.f = f;
  return (u16)((v.i + 0x7FFFu + ((v.i >> 16) & 1u)) >> 16);
}

// ---------------- LayerNorm + x->bf16 (one row per block) ----------------
__global__ void ln_prep(const float* __restrict__ x, const float* __restrict__ g,
                        const float* __restrict__ bta, u16* __restrict__ h,
                        u16* __restrict__ xb, float* __restrict__ loss){
  if (blockIdx.x == 0 && threadIdx.x == 0) loss[0] = 0.f;
  int row = blockIdx.x, tid = threadIdx.x;
  const float4* xr = (const float4*)(x + (size_t)row * 1024);
  float4 v = xr[tid];
  float s  = v.x + v.y + v.z + v.w;
  float s2 = v.x*v.x + v.y*v.y + v.z*v.z + v.w*v.w;
  #pragma unroll
  for (int o = 32; o > 0; o >>= 1){ s += __shfl_down(s, o); s2 += __shfl_down(s2, o); }
  __shared__ float red[8];
  if ((tid & 63) == 0){ red[tid >> 6] = s; red[4 + (tid >> 6)] = s2; }
  __syncthreads();
  float ts = red[0]+red[1]+red[2]+red[3];
  float t2 = red[4]+red[5]+red[6]+red[7];
  float mu   = ts * (1.0f/1024.0f);
  float var  = t2 * (1.0f/1024.0f) - mu*mu;
  float rstd = rsqrtf(var + 1e-5f);
  float4 gg = ((const float4*)g)[tid];
  float4 bb = ((const float4*)bta)[tid];
  ushort4 hv, xv;
  hv.x = f2bf((v.x-mu)*rstd*gg.x + bb.x);
  hv.y = f2bf((v.y-mu)*rstd*gg.y + bb.y);
  hv.z = f2bf((v.z-mu)*rstd*gg.z + bb.z);
  hv.w = f2bf((v.w-mu)*rstd*gg.w + bb.w);
  xv.x = f2bf(v.x); xv.y = f2bf(v.y); xv.z = f2bf(v.z); xv.w = f2bf(v.w);
  ((ushort4*)h )[(size_t)row*256 + tid] = hv;
  ((ushort4*)xb)[(size_t)row*256 + tid] = xv;
}

// ---------------- fp32 -> bf16 weight conversion (5 matrices) ----------------
__global__ void conv5(const float* __restrict__ a, const float* __restrict__ b,
                      const float* __restrict__ c, const float* __restrict__ d,
                      const float* __restrict__ e,
                      u16* oa, u16* ob, u16* oc, u16* od, u16* oe){
  int sel = blockIdx.y;
  const float* s = sel==0?a : sel==1?b : sel==2?c : sel==3?d : e;
  u16* o = sel==0?oa : sel==1?ob : sel==2?oc : sel==3?od : oe;
  int i = blockIdx.x*256 + threadIdx.x;   // 262144 float4's
  float4 v = ((const float4*)s)[i];
  ushort4 r; r.x=f2bf(v.x); r.y=f2bf(v.y); r.z=f2bf(v.z); r.w=f2bf(v.w);
  ((ushort4*)o)[i] = r;
}

// --------- WeffT[d][e] = W0[e][d] + sum_r A[e][r]*B[r][d], bf16 out ---------
__global__ void weff_k(const float* __restrict__ W0, const float* __restrict__ Ai,
                       const float* __restrict__ Bi, u16* __restrict__ Wet){
  __shared__ float tile[32][33];
  int d0 = blockIdx.x*32, e0 = blockIdx.y*32;
  int tid = threadIdx.x;
  int lr = tid >> 5, lc = tid & 31;
  #pragma unroll
  for (int s = 0; s < 4; ++s){
    int e = e0 + s*8 + lr, d = d0 + lc;
    float v = W0[(size_t)e*1024 + d];
    #pragma unroll
    for (int r = 0; r < 8; ++r) v += Ai[e*8 + r] * Bi[(size_t)r*1024 + d];
    tile[s*8 + lr][lc] = v;
  }
  __syncthreads();
  #pragma unroll
  for (int s = 0; s < 4; ++s){
    int d = d0 + s*8 + lr, e = e0 + lc;
    Wet[(size_t)d*1024 + e] = f2bf(tile[lc][s*8 + lr]);
  }
}

// =====================================================================
// 256x256 MFMA GEMM: C[m,n] = sum_k A[m,k]*Bm[n,k]  (K=1024)
// 8 waves (2Mx4N), K sliced at 32, 4-slot LDS ring (128 KiB),
// stage-ahead 3 slices, counted vmcnt(8), XOR bank swizzle.
// NEW (this round): each slice split into TWO 16-MFMA sub-phases with the
// m201 skeleton {ds_reads || stage-half -> barrier -> lgkmcnt(0) ->
// setprio(1) MFMA setprio(0) -> barrier} to restore LDS||matrix overlap
// (round-1 coarse 32-MFMA phases serialized the pipes: MfmaUtil 32%).
// =====================================================================
#define VMW(N)  asm volatile("s_waitcnt vmcnt(" #N ")" ::: "memory")
#define LGKM0   asm volatile("s_waitcnt lgkmcnt(0)" ::: "memory")
#define SBAR    __builtin_amdgcn_s_barrier()
#define SCHED0  __builtin_amdgcn_sched_barrier(0)

template<int EPI>
__device__ __forceinline__ void gemm256_body(const u16* __restrict__ A, const u16* __restrict__ Bm,
    u16* __restrict__ Cb, float* __restrict__ Cf, const float* __restrict__ lsg,
    const float* __restrict__ xres, int mblk, int nblk)
{
  __shared__ u16 As[4][8192];
  __shared__ u16 Bs[4][8192];
  const int tid  = threadIdx.x;
  const int lane = tid & 63;
  const int w    = tid >> 6;            // 0..7
  const int wm = w >> 2, wn = w & 3;    // 2 x 4 wave grid
  const int l15 = lane & 15, quad = lane >> 4;
  const int m0 = mblk * 256, n0 = nblk * 256;

  // ---- staging: linear LDS dest, inverse-swizzled global source ----
  const int sl   = (lane & 7) ^ (lane >> 3);
  const int srow = 2*(w*8 + (lane >> 3)) + (sl >> 2);
  const int scol = (sl & 3) * 8;
  const u16* gA = A  + (size_t)(m0 + srow)*1024 + scol;
  const u16* gB = Bm + (size_t)(n0 + srow)*1024 + scol;
  const int ldsOff = w * 512;           // elems; second half adds 4096

  // ---- swizzled read addresses (elems) ----
  const int phys8 = (((((l15 & 1) << 2) | quad) ^ (l15 >> 1))) * 8;
  const int rdA = (wm*64 + (l15 >> 1))*64 + phys8;
  const int rdB = (wn*32 + (l15 >> 1))*64 + phys8;

  f32x4 acc[8][4] = {};

#define SA(T) do{ const int _ss=(T)&3; const size_t _k=(size_t)(T)*32; \
    __builtin_amdgcn_global_load_lds((const __attribute__((address_space(1))) unsigned int*)(gA + _k), \
        (__attribute__((address_space(3))) unsigned int*)(&As[_ss][ldsOff]), 16, 0, 0); \
    __builtin_amdgcn_global_load_lds((const __attribute__((address_space(1))) unsigned int*)(gA + _k + 131072), \
        (__attribute__((address_space(3))) unsigned int*)(&As[_ss][ldsOff + 4096]), 16, 0, 0); \
  }while(0)
#define SB(T) do{ const int _ss=(T)&3; const size_t _k=(size_t)(T)*32; \
    __builtin_amdgcn_global_load_lds((const __attribute__((address_space(1))) unsigned int*)(gB + _k), \
        (__attribute__((address_space(3))) unsigned int*)(&Bs[_ss][ldsOff]), 16, 0, 0); \
    __builtin_amdgcn_global_load_lds((const __attribute__((address_space(1))) unsigned int*)(gB + _k + 131072), \
        (__attribute__((address_space(3))) unsigned int*)(&Bs[_ss][ldsOff + 4096]), 16, 0, 0); \
  }while(0)

// One K-32 slice = two 16-MFMA sub-phases.
// sp0: read B[0..1] + A[0..7] (10 ds_read_b128), stage A-half of T+3, MFMA j=0,1
// sp1: read B[2..3] (2), stage B-half of T+3, counted VMOP, MFMA j=2,3 (A reuse)
#define SLICE(T, DS, VMOP) do{ \
    const int _s = (T) & 3; \
    const u16* _as = &As[_s][0]; \
    const u16* _bs = &Bs[_s][0]; \
    short8 afv[8], bfv[4]; \
    bfv[0] = *(const short8*)(_bs + rdB); \
    bfv[1] = *(const short8*)(_bs + rdB + 512); \
    _Pragma("unroll") \
    for (int _i = 0; _i < 8; ++_i) afv[_i] = *(const short8*)(_as + rdA + _i*512); \
    if (DS) SA((T)+3); \
    SBAR; LGKM0; SCHED0; \
    __builtin_amdgcn_s_setprio(1); \
    _Pragma("unroll") \
    for (int _i = 0; _i < 8; ++_i){ \
      acc[_i][0] = __builtin_amdgcn_mfma_f32_16x16x32_bf16(afv[_i], bfv[0], acc[_i][0], 0, 0, 0); \
      acc[_i][1] = __builtin_amdgcn_mfma_f32_16x16x32_bf16(afv[_i], bfv[1], acc[_i][1], 0, 0, 0); \
    } \
    __builtin_amdgcn_s_setprio(0); SCHED0; SBAR; \
    bfv[2] = *(const short8*)(_bs + rdB + 1024); \
    bfv[3] = *(const short8*)(_bs + rdB + 1536); \
    if (DS) SB((T)+3); \
    VMOP; \
    SBAR; LGKM0; SCHED0; \
    __builtin_amdgcn_s_setprio(1); \
    _Pragma("unroll") \
    for (int _i = 0; _i < 8; ++_i){ \
      acc[_i][2] = __builtin_amdgcn_mfma_f32_16x16x32_bf16(afv[_i], bfv[2], acc[_i][2], 0, 0, 0); \
      acc[_i][3] = __builtin_amdgcn_mfma_f32_16x16x32_bf16(afv[_i], bfv[3], acc[_i][3], 0, 0, 0); \
    } \
    __builtin_amdgcn_s_setprio(0); SCHED0; SBAR; \
  }while(0)

  // prologue: 3 slices in flight; vmcnt(8) -> slice 0 landed chip-wide
  SA(0); SB(0); SA(1); SB(1); SA(2); SB(2);
  VMW(8);
  SBAR;

  #pragma unroll 1
  for (int t = 0; t < 28; t += 4){
    SLICE(t+0, 1, VMW(8));
    SLICE(t+1, 1, VMW(8));
    SLICE(t+2, 1, VMW(8));
    SLICE(t+3, 1, VMW(8));
  }
  SLICE(28, 1, VMW(8));   // stages slice 31 (last)
  SLICE(29, 0, VMW(4));   // outstanding {30,31} -> 30 landed
  SLICE(30, 0, VMW(0));   // outstanding {31}    -> 31 landed
  SLICE(31, 0, (void)0);
#undef SLICE
#undef SA
#undef SB

  // ---- epilogue: C/D layout col=lane&15, row=quad*4+r (verified) ----
  const int rbase = quad * 4;
  if (EPI == 0){
    #pragma unroll
    for (int i = 0; i < 8; ++i){
      int row = m0 + wm*128 + i*16 + rbase;
      #pragma unroll
      for (int j = 0; j < 4; ++j){
        int col = n0 + wn*64 + j*16 + l15;
        #pragma unroll
        for (int r = 0; r < 4; ++r)
          Cb[(size_t)(row + r)*1024 + col] = f2bf(acc[i][j][r]);
      }
    }
  } else {
    float lsv[4];
    #pragma unroll
    for (int j = 0; j < 4; ++j) lsv[j] = lsg[n0 + wn*64 + j*16 + l15];
    #pragma unroll
    for (int i = 0; i < 8; ++i){
      int row = m0 + wm*128 + i*16 + rbase;
      #pragma unroll
      for (int j = 0; j < 4; ++j){
        int col = n0 + wn*64 + j*16 + l15;
        #pragma unroll
        for (int r = 0; r < 4; ++r){
          size_t idx = (size_t)(row + r)*1024 + col;
          Cf[idx] = acc[i][j][r] * lsv[j] + xres[idx];
        }
      }
    }
  }
}

// fused Q/K/V/Gate GEMM: 1024 blocks; XCD-swizzled, A-panel-major layout
__global__ __launch_bounds__(512, 2) void gemm_qkvg(
    const u16* __restrict__ h, const u16* __restrict__ xb,
    const u16* __restrict__ Wqb, const u16* __restrict__ Wkb,
    const u16* __restrict__ Wvb, const u16* __restrict__ Wgb,
    u16* __restrict__ Qb, u16* __restrict__ Kb,
    u16* __restrict__ Vb, u16* __restrict__ Gb){
  int bid = blockIdx.x;                       // 1024 = 8 XCD chunks of 128
  int swz = (bid & 7) * 128 + (bid >> 3);     // bijective (1024 % 8 == 0)
  int mblk = swz >> 4;                        // 64 m-blocks; 8 per XCD chunk
  int rem  = swz & 15;
  int sel  = rem >> 2, nblk = rem & 3;
  const u16* A  = (sel == 3) ? xb : h;
  const u16* Bm = sel==0?Wqb : sel==1?Wkb : sel==2?Wvb : Wgb;
  u16* Out      = sel==0?Qb  : sel==1?Kb  : sel==2?Vb  : Gb;
  gemm256_body<0>(A, Bm, Out, nullptr, nullptr, nullptr, mblk, nblk);
}

__global__ __launch_bounds__(512, 2) void gemm_plain(
    const u16* __restrict__ A, const u16* __restrict__ Bm, u16* __restrict__ C){
  int bid = blockIdx.x;                       // 256
  int swz = (bid & 7) * 32 + (bid >> 3);
  gemm256_body<0>(A, Bm, C, nullptr, nullptr, nullptr, swz >> 2, swz & 3);
}

__global__ __launch_bounds__(512, 2) void gemm_final(
    const u16* __restrict__ A, const u16* __restrict__ Bm,
    float* __restrict__ C, const float* __restrict__ lsg,
    const float* __restrict__ xres){
  int bid = blockIdx.x;                       // 256
  int swz = (bid & 7) * 32 + (bid >> 3);
  gemm256_body<1>(A, Bm, nullptr, C, lsg, xres, swz >> 2, swz & 3);
}

// ---------------- scan pass 1: per-chunk gradient sums + loss ----------------
// grid (4, 32, 4): (c-block, chunk, batch); chunk = 128 timesteps
__global__ void scan1(const u16* __restrict__ Kb, const u16* __restrict__ Vb,
                      const u16* __restrict__ Yb, float* __restrict__ part,
                      float* __restrict__ loss){
  int tid = threadIdx.x;
  int c = blockIdx.x*256 + tid;
  int ch = blockIdx.y, b = blockIdx.z;
  size_t base = ((size_t)b*4096 + (size_t)ch*128)*1024 + c;
  float g = 0.f, ls = 0.f;
  #pragma unroll 8
  for (int t = 0; t < 128; ++t){
    size_t idx = base + (size_t)t*1024;
    float kv = bf2f(Kb[idx]), vv = bf2f(Vb[idx]), yv = bf2f(Yb[idx]);
    float e = yv - vv;
    g += kv*e; ls += e*e;
  }
  part[((size_t)(b*32 + ch))*1024 + c] = g;
  #pragma unroll
  for (int o = 32; o > 0; o >>= 1) ls += __shfl_down(ls, o);
  __shared__ float red[4];
  if ((tid & 63) == 0) red[tid >> 6] = ls;
  __syncthreads();
  if (tid == 0) atomicAdd(loss, red[0]+red[1]+red[2]+red[3]);
}

// -------- scan pass 2: out_pre = (y0 - Q*lr*shift*pos_scale)*sigmoid(G) ------
__global__ void scan2(const u16* __restrict__ Kb, const u16* __restrict__ Vb,
                      const u16* __restrict__ Yb, const u16* __restrict__ Qb,
                      const u16* __restrict__ Gb, const float* __restrict__ part,
                      const float* __restrict__ llr, u16* __restrict__ OutPre){
  int tid = threadIdx.x;
  int c = blockIdx.x*256 + tid;
  int ch = blockIdx.y, b = blockIdx.z;
  float run = 0.f;
  for (int j = 0; j < ch; ++j) run += part[((size_t)(b*32 + j))*1024 + c];
  float lrc = fminf(expf(llr[c]), 1.0f);
  size_t base = ((size_t)b*4096 + (size_t)ch*128)*1024 + c;
  #pragma unroll 4
  for (int t = 0; t < 128; ++t){
    size_t idx = base + (size_t)t*1024;
    float kv = bf2f(Kb[idx]), vv = bf2f(Vb[idx]), yv = bf2f(Yb[idx]);
    float qv = bf2f(Qb[idx]), gl = bf2f(Gb[idx]);
    float e = yv - vv;
    int tg = ch*128 + t + 1;
    float ps = 1.0f/(1.0f + 0.1f*logf((float)tg));
    float gate = 1.0f/(1.0f + expf(-gl));
    float o = (yv - qv*lrc*run*ps) * gate;
    OutPre[idx] = f2bf(o);     // same buffer as Qb: read-before-write per element
    run += kv*e;
  }
}

__global__ void finloss(const float* __restrict__ loss, float* __restrict__ o){
  o[0] = loss[0] * (1.0f/16777216.0f);
}

extern "C" void kernel_launch(void* const* d_in, const int* in_sizes, int n_in,
                              void* d_out, int out_size, void* d_ws, size_t ws_size,
                              hipStream_t stream){
  const float* x   = (const float*)d_in[0];
  const float* W0  = (const float*)d_in[1];
  const float* Ai  = (const float*)d_in[2];
  const float* Bi  = (const float*)d_in[3];
  const float* llr = (const float*)d_in[4];
  const float* Wq  = (const float*)d_in[5];
  const float* Wk  = (const float*)d_in[6];
  const float* Wv  = (const float*)d_in[7];
  const float* Wo  = (const float*)d_in[8];
  const float* Wg  = (const float*)d_in[9];
  const float* lng = (const float*)d_in[10];
  const float* lnb = (const float*)d_in[11];
  const float* lsg = (const float*)d_in[12];
  float* out = (float*)d_out;

  const size_t TOK = 16384, CC = 1024;
  char* p = (char*)d_ws;
  float* loss = (float*)p; p += 256;
  u16* h   = (u16*)p; p += TOK*CC*2;   // reused as y0 after GEMM1
  u16* xb  = (u16*)p; p += TOK*CC*2;
  u16* Qb  = (u16*)p; p += TOK*CC*2;   // reused as out_pre in scan2
  u16* Kb  = (u16*)p; p += TOK*CC*2;
  u16* Vb  = (u16*)p; p += TOK*CC*2;
  u16* Gb  = (u16*)p; p += TOK*CC*2;
  u16* Wqb = (u16*)p; p += CC*CC*2;
  u16* Wkb = (u16*)p; p += CC*CC*2;
  u16* Wvb = (u16*)p; p += CC*CC*2;
  u16* Wgb = (u16*)p; p += CC*CC*2;
  u16* Wob = (u16*)p; p += CC*CC*2;
  u16* Wet = (u16*)p; p += CC*CC*2;
  float* part = (float*)p; p += (size_t)4*32*1024*4;

  ln_prep<<<16384, 256, 0, stream>>>(x, lng, lnb, h, xb, loss);
  conv5<<<dim3(1024, 5), 256, 0, stream>>>(Wq, Wk, Wv, Wg, Wo, Wqb, Wkb, Wvb, Wgb, Wob);
  weff_k<<<dim3(32, 32), 256, 0, stream>>>(W0, Ai, Bi, Wet);
  gemm_qkvg<<<1024, 512, 0, stream>>>(h, xb, Wqb, Wkb, Wvb, Wgb, Qb, Kb, Vb, Gb);
  gemm_plain<<<256, 512, 0, stream>>>(Kb, Wet, h);                 // y0 -> h buffer
  scan1<<<dim3(4, 32, 4), 256, 0, stream>>>(Kb, Vb, h, part, loss);
  scan2<<<dim3(4, 32, 4), 256, 0, stream>>>(Kb, Vb, h, Qb, Gb, part, llr, Qb);
  gemm_final<<<256, 512, 0, stream>>>(Qb, Wob, out, lsg, x);
  finloss<<<1, 1, 0, stream>>>(loss, out + 16777216);
}

// Round 3
// 430.667 us; speedup vs baseline: 1.1510x; 1.0638x over previous
//
#include <hip/hip_runtime.h>
#include <stdint.h>
#include <math.h>

typedef unsigned short u16;
typedef __attribute__((ext_vector_type(8))) short short8;
typedef __attribute__((ext_vector_type(4))) float f32x4;

__device__ __forceinline__ float bf2f(u16 u){
  union { unsigned int i; float f; } v; v.i = ((unsigned int)u) << 16; return v.f;
}
__device__ __forceinline__ u16 f2bf(float f){
  union { float f; unsigned int i; } v; v.f = f;
  return (u16)((v.i + 0x7FFFu + ((v.i >> 16) & 1u)) >> 16);
}

// ---------------- LayerNorm + x->bf16 (one row per block) ----------------
__global__ void ln_prep(const float* __restrict__ x, const float* __restrict__ g,
                        const float* __restrict__ bta, u16* __restrict__ h,
                        u16* __restrict__ xb, float* __restrict__ loss){
  if (blockIdx.x == 0 && threadIdx.x == 0) loss[0] = 0.f;
  int row = blockIdx.x, tid = threadIdx.x;
  const float4* xr = (const float4*)(x + (size_t)row * 1024);
  float4 v = xr[tid];
  float s  = v.x + v.y + v.z + v.w;
  float s2 = v.x*v.x + v.y*v.y + v.z*v.z + v.w*v.w;
  #pragma unroll
  for (int o = 32; o > 0; o >>= 1){ s += __shfl_down(s, o); s2 += __shfl_down(s2, o); }
  __shared__ float red[8];
  if ((tid & 63) == 0){ red[tid >> 6] = s; red[4 + (tid >> 6)] = s2; }
  __syncthreads();
  float ts = red[0]+red[1]+red[2]+red[3];
  float t2 = red[4]+red[5]+red[6]+red[7];
  float mu   = ts * (1.0f/1024.0f);
  float var  = t2 * (1.0f/1024.0f) - mu*mu;
  float rstd = rsqrtf(var + 1e-5f);
  float4 gg = ((const float4*)g)[tid];
  float4 bb = ((const float4*)bta)[tid];
  ushort4 hv, xv;
  hv.x = f2bf((v.x-mu)*rstd*gg.x + bb.x);
  hv.y = f2bf((v.y-mu)*rstd*gg.y + bb.y);
  hv.z = f2bf((v.z-mu)*rstd*gg.z + bb.z);
  hv.w = f2bf((v.w-mu)*rstd*gg.w + bb.w);
  xv.x = f2bf(v.x); xv.y = f2bf(v.y); xv.z = f2bf(v.z); xv.w = f2bf(v.w);
  ((ushort4*)h )[(size_t)row*256 + tid] = hv;
  ((ushort4*)xb)[(size_t)row*256 + tid] = xv;
}

// ---------------- fp32 -> bf16 weight conversion (5 matrices) ----------------
__global__ void conv5(const float* __restrict__ a, const float* __restrict__ b,
                      const float* __restrict__ c, const float* __restrict__ d,
                      const float* __restrict__ e,
                      u16* oa, u16* ob, u16* oc, u16* od, u16* oe){
  int sel = blockIdx.y;
  const float* s = sel==0?a : sel==1?b : sel==2?c : sel==3?d : e;
  u16* o = sel==0?oa : sel==1?ob : sel==2?oc : sel==3?od : oe;
  int i = blockIdx.x*256 + threadIdx.x;   // 262144 float4's
  float4 v = ((const float4*)s)[i];
  ushort4 r; r.x=f2bf(v.x); r.y=f2bf(v.y); r.z=f2bf(v.z); r.w=f2bf(v.w);
  ((ushort4*)o)[i] = r;
}

// --------- WeffT[d][e] = W0[e][d] + sum_r A[e][r]*B[r][d], bf16 out ---------
__global__ void weff_k(const float* __restrict__ W0, const float* __restrict__ Ai,
                       const float* __restrict__ Bi, u16* __restrict__ Wet){
  __shared__ float tile[32][33];
  int d0 = blockIdx.x*32, e0 = blockIdx.y*32;
  int tid = threadIdx.x;
  int lr = tid >> 5, lc = tid & 31;
  #pragma unroll
  for (int s = 0; s < 4; ++s){
    int e = e0 + s*8 + lr, d = d0 + lc;
    float v = W0[(size_t)e*1024 + d];
    #pragma unroll
    for (int r = 0; r < 8; ++r) v += Ai[e*8 + r] * Bi[(size_t)r*1024 + d];
    tile[s*8 + lr][lc] = v;
  }
  __syncthreads();
  #pragma unroll
  for (int s = 0; s < 4; ++s){
    int d = d0 + s*8 + lr, e = e0 + lc;
    Wet[(size_t)d*1024 + e] = f2bf(tile[lc][s*8 + lr]);
  }
}

// =====================================================================
// 256x256 MFMA GEMM: C[m,n] = sum_k A[m,k]*Bm[n,k]  (K=1024)
// 8 waves (2Mx4N), K sliced at 32, 4-slot LDS ring (128 KiB),
// stage-ahead 3 slices, counted vmcnt(8) (never 0 until the tail),
// XOR bank swizzle (both-sides: pre-swizzled global src + swizzled read).
// ROUND 3: ONE barrier + ZERO explicit lgkm waits per slice. Rounds 1/2
// lockstepped reads-then-MFMA chip-wide (MfmaUtil 32-37%). Now each wave
// free-runs within a slice (stage -> 12 ds_read -> 32 MFMA with compiler
// fine-grained lgkmcnt), so waves stagger and LDS || matrix overlap.
// Race ledger:
//  - reads of slot t: own VMW(8) proves own slice-t loads landed; the
//    barrier then proves it for all waves' loads.
//  - stage(t+3) overwrites slot t-1: every wave consumed its slot-(t-1)
//    reads (dataflow) before reaching this slice's barrier; stage is
//    fenced after the barrier by sched_barrier(0).
//  - vmcnt FIFO: 4 loads/slice, 3 slices ahead -> VMW(8) == slice t
//    landed; tail drains 8 -> 4 -> 0.
// =====================================================================
#define VMW(N)  asm volatile("s_waitcnt vmcnt(" #N ")" ::: "memory")
#define SBAR    __builtin_amdgcn_s_barrier()
#define SCHED0  __builtin_amdgcn_sched_barrier(0)

template<int EPI>
__device__ __forceinline__ void gemm256_body(const u16* __restrict__ A, const u16* __restrict__ Bm,
    u16* __restrict__ Cb, float* __restrict__ Cf, const float* __restrict__ lsg,
    const float* __restrict__ xres, int mblk, int nblk)
{
  __shared__ u16 As[4][8192];
  __shared__ u16 Bs[4][8192];
  const int tid  = threadIdx.x;
  const int lane = tid & 63;
  const int w    = tid >> 6;            // 0..7
  const int wm = w >> 2, wn = w & 3;    // 2 x 4 wave grid
  const int l15 = lane & 15, quad = lane >> 4;
  const int m0 = mblk * 256, n0 = nblk * 256;

  // ---- staging: linear LDS dest, inverse-swizzled global source ----
  const int sl   = (lane & 7) ^ (lane >> 3);
  const int srow = 2*(w*8 + (lane >> 3)) + (sl >> 2);
  const int scol = (sl & 3) * 8;
  const u16* gA = A  + (size_t)(m0 + srow)*1024 + scol;
  const u16* gB = Bm + (size_t)(n0 + srow)*1024 + scol;
  const int ldsOff = w * 512;           // elems; second half adds 4096

  // ---- swizzled read addresses (elems) ----
  const int phys8 = (((((l15 & 1) << 2) | quad) ^ (l15 >> 1))) * 8;
  const int rdA = (wm*64 + (l15 >> 1))*64 + phys8;
  const int rdB = (wn*32 + (l15 >> 1))*64 + phys8;

  f32x4 acc[8][4] = {};

#define SA(T) do{ const int _ss=(T)&3; const size_t _k=(size_t)(T)*32; \
    __builtin_amdgcn_global_load_lds((const __attribute__((address_space(1))) unsigned int*)(gA + _k), \
        (__attribute__((address_space(3))) unsigned int*)(&As[_ss][ldsOff]), 16, 0, 0); \
    __builtin_amdgcn_global_load_lds((const __attribute__((address_space(1))) unsigned int*)(gA + _k + 131072), \
        (__attribute__((address_space(3))) unsigned int*)(&As[_ss][ldsOff + 4096]), 16, 0, 0); \
  }while(0)
#define SB(T) do{ const int _ss=(T)&3; const size_t _k=(size_t)(T)*32; \
    __builtin_amdgcn_global_load_lds((const __attribute__((address_space(1))) unsigned int*)(gB + _k), \
        (__attribute__((address_space(3))) unsigned int*)(&Bs[_ss][ldsOff]), 16, 0, 0); \
    __builtin_amdgcn_global_load_lds((const __attribute__((address_space(1))) unsigned int*)(gB + _k + 131072), \
        (__attribute__((address_space(3))) unsigned int*)(&Bs[_ss][ldsOff + 4096]), 16, 0, 0); \
  }while(0)

// One K-32 slice: counted vm-wait, single barrier, then free-running
// stage + reads + 32 MFMAs (compiler inserts fine-grained lgkmcnt).
#define SLICE(T, VMOP, DS) do{ \
    VMOP; \
    SCHED0; SBAR; SCHED0; \
    if (DS){ SA((T)+3); SB((T)+3); } \
    const int _s = (T) & 3; \
    const u16* _as = &As[_s][0]; \
    const u16* _bs = &Bs[_s][0]; \
    short8 afv[8], bfv[4]; \
    _Pragma("unroll") \
    for (int _j = 0; _j < 4; ++_j) bfv[_j] = *(const short8*)(_bs + rdB + _j*512); \
    _Pragma("unroll") \
    for (int _i = 0; _i < 8; ++_i) afv[_i] = *(const short8*)(_as + rdA + _i*512); \
    _Pragma("unroll") \
    for (int _i = 0; _i < 8; ++_i){ \
      _Pragma("unroll") \
      for (int _j = 0; _j < 4; ++_j) \
        acc[_i][_j] = __builtin_amdgcn_mfma_f32_16x16x32_bf16(afv[_i], bfv[_j], acc[_i][_j], 0, 0, 0); \
    } \
  }while(0)

  // prologue: 3 slices in flight
  SA(0); SB(0); SA(1); SB(1); SA(2); SB(2);

  #pragma unroll 1
  for (int t = 0; t < 28; t += 4){
    SLICE(t+0, VMW(8), 1);
    SLICE(t+1, VMW(8), 1);
    SLICE(t+2, VMW(8), 1);
    SLICE(t+3, VMW(8), 1);
  }
  SLICE(28, VMW(8), 1);   // stages slice 31 (last)
  SLICE(29, VMW(8), 0);   // outstanding {29,30,31}=12 -> 8 => 29 landed
  SLICE(30, VMW(4), 0);   // outstanding {30,31}=8 -> 4    => 30 landed
  SLICE(31, VMW(0), 0);   // outstanding {31}=4 -> 0       => 31 landed
#undef SLICE
#undef SA
#undef SB

  // ---- epilogue: C/D layout col=lane&15, row=quad*4+r (verified) ----
  const int rbase = quad * 4;
  if (EPI == 0){
    #pragma unroll
    for (int i = 0; i < 8; ++i){
      int row = m0 + wm*128 + i*16 + rbase;
      #pragma unroll
      for (int j = 0; j < 4; ++j){
        int col = n0 + wn*64 + j*16 + l15;
        #pragma unroll
        for (int r = 0; r < 4; ++r)
          Cb[(size_t)(row + r)*1024 + col] = f2bf(acc[i][j][r]);
      }
    }
  } else {
    float lsv[4];
    #pragma unroll
    for (int j = 0; j < 4; ++j) lsv[j] = lsg[n0 + wn*64 + j*16 + l15];
    #pragma unroll
    for (int i = 0; i < 8; ++i){
      int row = m0 + wm*128 + i*16 + rbase;
      #pragma unroll
      for (int j = 0; j < 4; ++j){
        int col = n0 + wn*64 + j*16 + l15;
        #pragma unroll
        for (int r = 0; r < 4; ++r){
          size_t idx = (size_t)(row + r)*1024 + col;
          Cf[idx] = acc[i][j][r] * lsv[j] + xres[idx];
        }
      }
    }
  }
}

// fused Q/K/V/Gate GEMM: 1024 blocks; XCD-swizzled, A-panel-major layout
__global__ __launch_bounds__(512, 2) void gemm_qkvg(
    const u16* __restrict__ h, const u16* __restrict__ xb,
    const u16* __restrict__ Wqb, const u16* __restrict__ Wkb,
    const u16* __restrict__ Wvb, const u16* __restrict__ Wgb,
    u16* __restrict__ Qb, u16* __restrict__ Kb,
    u16* __restrict__ Vb, u16* __restrict__ Gb){
  int bid = blockIdx.x;                       // 1024 = 8 XCD chunks of 128
  int swz = (bid & 7) * 128 + (bid >> 3);     // bijective (1024 % 8 == 0)
  int mblk = swz >> 4;                        // 64 m-blocks; 8 per XCD chunk
  int rem  = swz & 15;
  int sel  = rem >> 2, nblk = rem & 3;
  const u16* A  = (sel == 3) ? xb : h;
  const u16* Bm = sel==0?Wqb : sel==1?Wkb : sel==2?Wvb : Wgb;
  u16* Out      = sel==0?Qb  : sel==1?Kb  : sel==2?Vb  : Gb;
  gemm256_body<0>(A, Bm, Out, nullptr, nullptr, nullptr, mblk, nblk);
}

__global__ __launch_bounds__(512, 2) void gemm_plain(
    const u16* __restrict__ A, const u16* __restrict__ Bm, u16* __restrict__ C){
  int bid = blockIdx.x;                       // 256
  int swz = (bid & 7) * 32 + (bid >> 3);
  gemm256_body<0>(A, Bm, C, nullptr, nullptr, nullptr, swz >> 2, swz & 3);
}

__global__ __launch_bounds__(512, 2) void gemm_final(
    const u16* __restrict__ A, const u16* __restrict__ Bm,
    float* __restrict__ C, const float* __restrict__ lsg,
    const float* __restrict__ xres){
  int bid = blockIdx.x;                       // 256
  int swz = (bid & 7) * 32 + (bid >> 3);
  gemm256_body<1>(A, Bm, nullptr, C, lsg, xres, swz >> 2, swz & 3);
}

// ---------------- scan pass 1: per-chunk gradient sums + loss ----------------
// grid (4, 32, 4): (c-block, chunk, batch); chunk = 128 timesteps
__global__ void scan1(const u16* __restrict__ Kb, const u16* __restrict__ Vb,
                      const u16* __restrict__ Yb, float* __restrict__ part,
                      float* __restrict__ loss){
  int tid = threadIdx.x;
  int c = blockIdx.x*256 + tid;
  int ch = blockIdx.y, b = blockIdx.z;
  size_t base = ((size_t)b*4096 + (size_t)ch*128)*1024 + c;
  float g = 0.f, ls = 0.f;
  #pragma unroll 8
  for (int t = 0; t < 128; ++t){
    size_t idx = base + (size_t)t*1024;
    float kv = bf2f(Kb[idx]), vv = bf2f(Vb[idx]), yv = bf2f(Yb[idx]);
    float e = yv - vv;
    g += kv*e; ls += e*e;
  }
  part[((size_t)(b*32 + ch))*1024 + c] = g;
  #pragma unroll
  for (int o = 32; o > 0; o >>= 1) ls += __shfl_down(ls, o);
  __shared__ float red[4];
  if ((tid & 63) == 0) red[tid >> 6] = ls;
  __syncthreads();
  if (tid == 0) atomicAdd(loss, red[0]+red[1]+red[2]+red[3]);
}

// -------- scan pass 2: out_pre = (y0 - Q*lr*shift*pos_scale)*sigmoid(G) ------
__global__ void scan2(const u16* __restrict__ Kb, const u16* __restrict__ Vb,
                      const u16* __restrict__ Yb, const u16* __restrict__ Qb,
                      const u16* __restrict__ Gb, const float* __restrict__ part,
                      const float* __restrict__ llr, u16* __restrict__ OutPre){
  int tid = threadIdx.x;
  int c = blockIdx.x*256 + tid;
  int ch = blockIdx.y, b = blockIdx.z;
  float run = 0.f;
  for (int j = 0; j < ch; ++j) run += part[((size_t)(b*32 + j))*1024 + c];
  float lrc = fminf(expf(llr[c]), 1.0f);
  size_t base = ((size_t)b*4096 + (size_t)ch*128)*1024 + c;
  #pragma unroll 4
  for (int t = 0; t < 128; ++t){
    size_t idx = base + (size_t)t*1024;
    float kv = bf2f(Kb[idx]), vv = bf2f(Vb[idx]), yv = bf2f(Yb[idx]);
    float qv = bf2f(Qb[idx]), gl = bf2f(Gb[idx]);
    float e = yv - vv;
    int tg = ch*128 + t + 1;
    float ps = 1.0f/(1.0f + 0.1f*logf((float)tg));
    float gate = 1.0f/(1.0f + expf(-gl));
    float o = (yv - qv*lrc*run*ps) * gate;
    OutPre[idx] = f2bf(o);     // same buffer as Qb: read-before-write per element
    run += kv*e;
  }
}

__global__ void finloss(const float* __restrict__ loss, float* __restrict__ o){
  o[0] = loss[0] * (1.0f/16777216.0f);
}

extern "C" void kernel_launch(void* const* d_in, const int* in_sizes, int n_in,
                              void* d_out, int out_size, void* d_ws, size_t ws_size,
                              hipStream_t stream){
  const float* x   = (const float*)d_in[0];
  const float* W0  = (const float*)d_in[1];
  const float* Ai  = (const float*)d_in[2];
  const float* Bi  = (const float*)d_in[3];
  const float* llr = (const float*)d_in[4];
  const float* Wq  = (const float*)d_in[5];
  const float* Wk  = (const float*)d_in[6];
  const float* Wv  = (const float*)d_in[7];
  const float* Wo  = (const float*)d_in[8];
  const float* Wg  = (const float*)d_in[9];
  const float* lng = (const float*)d_in[10];
  const float* lnb = (const float*)d_in[11];
  const float* lsg = (const float*)d_in[12];
  float* out = (float*)d_out;

  const size_t TOK = 16384, CC = 1024;
  char* p = (char*)d_ws;
  float* loss = (float*)p; p += 256;
  u16* h   = (u16*)p; p += TOK*CC*2;   // reused as y0 after GEMM1
  u16* xb  = (u16*)p; p += TOK*CC*2;
  u16* Qb  = (u16*)p; p += TOK*CC*2;   // reused as out_pre in scan2
  u16* Kb  = (u16*)p; p += TOK*CC*2;
  u16* Vb  = (u16*)p; p += TOK*CC*2;
  u16* Gb  = (u16*)p; p += TOK*CC*2;
  u16* Wqb = (u16*)p; p += CC*CC*2;
  u16* Wkb = (u16*)p; p += CC*CC*2;
  u16* Wvb = (u16*)p; p += CC*CC*2;
  u16* Wgb = (u16*)p; p += CC*CC*2;
  u16* Wob = (u16*)p; p += CC*CC*2;
  u16* Wet = (u16*)p; p += CC*CC*2;
  float* part = (float*)p; p += (size_t)4*32*1024*4;

  ln_prep<<<16384, 256, 0, stream>>>(x, lng, lnb, h, xb, loss);
  conv5<<<dim3(1024, 5), 256, 0, stream>>>(Wq, Wk, Wv, Wg, Wo, Wqb, Wkb, Wvb, Wgb, Wob);
  weff_k<<<dim3(32, 32), 256, 0, stream>>>(W0, Ai, Bi, Wet);
  gemm_qkvg<<<1024, 512, 0, stream>>>(h, xb, Wqb, Wkb, Wvb, Wgb, Qb, Kb, Vb, Gb);
  gemm_plain<<<256, 512, 0, stream>>>(Kb, Wet, h);                 // y0 -> h buffer
  scan1<<<dim3(4, 32, 4), 256, 0, stream>>>(Kb, Vb, h, part, loss);
  scan2<<<dim3(4, 32, 4), 256, 0, stream>>>(Kb, Vb, h, Qb, Gb, part, llr, Qb);
  gemm_final<<<256, 512, 0, stream>>>(Qb, Wob, out, lsg, x);
  finloss<<<1, 1, 0, stream>>>(loss, out + 16777216);
}